// Round 1
// 1299.974 us; speedup vs baseline: 1.1095x; 1.1095x over previous
//
#include <hip/hip_runtime.h>
#include <math.h>

#define NUSER 100000
#define NITEM 100000
#define NEDGE 800000
#define DIN 128
#define HD 256
#define BM 64
#define BK 64

typedef __attribute__((ext_vector_type(8))) short bf16x8;
typedef __attribute__((ext_vector_type(4))) float f32x4;

__device__ __forceinline__ float gelu_f(float x) {
    return 0.5f * x * (1.0f + erff(x * 0.70710678118654752440f));
}
__device__ __forceinline__ unsigned short f2bf(float f) {
    union { unsigned int i; float f; } v; v.f = f;
    unsigned int r = (v.i + 0x7FFFu + ((v.i >> 16) & 1u)) >> 16;  // RNE
    return (unsigned short)r;
}
__device__ __forceinline__ float bflo(unsigned int p) {  // low bf16 of packed pair
    union { unsigned int i; float f; } v; v.i = p << 16; return v.f;
}
__device__ __forceinline__ float bfhi(unsigned int p) {  // high bf16 of packed pair
    union { unsigned int i; float f; } v; v.i = p & 0xFFFF0000u; return v.f;
}

// ---------------- CSR build ----------------
__global__ void k_hist(const int* __restrict__ dst, int* __restrict__ cnt, int n) {
    for (int i = blockIdx.x * blockDim.x + threadIdx.x; i < n; i += gridDim.x * blockDim.x)
        atomicAdd(&cnt[dst[i]], 1);
}

// Chunked exclusive scan, phase 1: each block scans one 8192-element chunk
// (8 elems/thread sequential + wave shfl scan + 16-entry LDS wave-sum scan;
// ONE barrier per block instead of k_scan2's ~2940 serial barriers).
// Grid covers both arrays: blocks [0,nb0) -> array0, [nb0,nb0+nb1) -> array1.
#define SCHUNK 8192
__global__ __launch_bounds__(1024) void k_scan_part(
    const int* __restrict__ cnt0, int* __restrict__ rp0, int n0, int nb0, int* __restrict__ csum0,
    const int* __restrict__ cnt1, int* __restrict__ rp1, int n1, int* __restrict__ csum1) {
    const int b = blockIdx.x;
    const int* cnt; int* rp; int n; int* csum; int chunk;
    if (b < nb0) { cnt = cnt0; rp = rp0; n = n0; csum = csum0; chunk = b; }
    else         { cnt = cnt1; rp = rp1; n = n1; csum = csum1; chunk = b - nb0; }
    const int t = threadIdx.x;
    const int lane = t & 63, wid = t >> 6;
    const int base = chunk * SCHUNK + t * 8;

    int v[8]; int s = 0;
    #pragma unroll
    for (int k = 0; k < 8; ++k) {
        int idx = base + k;
        int x = (idx < n) ? cnt[idx] : 0;
        v[k] = s; s += x;          // v[k] = exclusive within thread
    }
    // wave-inclusive scan of per-thread sums
    int ws = s;
    #pragma unroll
    for (int off = 1; off < 64; off <<= 1) {
        int y = __shfl_up(ws, off, 64);
        if (lane >= off) ws += y;
    }
    __shared__ int wsum[16];
    if (lane == 63) wsum[wid] = ws;
    __syncthreads();
    int wexc = 0;
    for (int w = 0; w < wid; ++w) wexc += wsum[w];  // LDS broadcast, uniform per wave
    const int texc = wexc + (ws - s);               // exclusive offset of thread in chunk
    #pragma unroll
    for (int k = 0; k < 8; ++k) {
        int idx = base + k;
        if (idx < n) rp[idx] = texc + v[k];         // chunk-local exclusive scan
    }
    if (t == 1023) csum[chunk] = texc + s;          // chunk total
}

// Phase 2: add chunk offsets (each block sums its <=13 preceding chunk totals),
// write cur, and write rp[n].
__global__ __launch_bounds__(1024) void k_scan_fin(
    int* __restrict__ rp0, int* __restrict__ cur0, int n0, int nb0, const int* __restrict__ csum0,
    int* __restrict__ rp1, int* __restrict__ cur1, int n1, int nb1, const int* __restrict__ csum1) {
    const int b = blockIdx.x;
    int* rp; int* cur; int n; const int* csum; int chunk; int nb;
    if (b < nb0) { rp = rp0; cur = cur0; n = n0; csum = csum0; chunk = b;       nb = nb0; }
    else         { rp = rp1; cur = cur1; n = n1; csum = csum1; chunk = b - nb0; nb = nb1; }
    int off = 0;
    for (int w = 0; w < chunk; ++w) off += csum[w];
    const int t = threadIdx.x;
    const int base = chunk * SCHUNK + t;
    #pragma unroll
    for (int k = 0; k < 8; ++k) {
        int idx = base + k * 1024;                  // coalesced
        if (idx < n) { int x = rp[idx] + off; rp[idx] = x; cur[idx] = x; }
    }
    if (chunk == nb - 1 && t == 0) rp[n] = off + csum[nb - 1];
}

__global__ void k_scatter(const int* __restrict__ src, const int* __restrict__ dst,
                          int* __restrict__ cur, int* __restrict__ sl, int n) {
    for (int i = blockIdx.x * blockDim.x + threadIdx.x; i < n; i += gridDim.x * blockDim.x) {
        int p = atomicAdd(&cur[dst[i]], 1);
        sl[p] = src[i];
    }
}

// ---------------- dtype prep ----------------
// f32 -> bf16 elementwise, 4 elems/thread
__global__ void k_cvt(const float* __restrict__ src, unsigned short* __restrict__ dst, int n4) {
    int i = blockIdx.x * blockDim.x + threadIdx.x;
    if (i < n4) {
        const float4 v = *(const float4*)(src + 4 * (size_t)i);
        unsigned int lo = (unsigned int)f2bf(v.x) | ((unsigned int)f2bf(v.y) << 16);
        unsigned int hi = (unsigned int)f2bf(v.z) | ((unsigned int)f2bf(v.w) << 16);
        uint2 o = {lo, hi};
        *(uint2*)(dst + 4 * (size_t)i) = o;
    }
}

// W f32 [K,256] -> WT bf16 [256][Kt] (transposed, at k-offset koff)
__global__ void k_cvtT(const float* __restrict__ src, unsigned short* __restrict__ dst,
                       int K, int Kt, int koff) {
    int i = blockIdx.x * blockDim.x + threadIdx.x;
    if (i < K * 256) {
        int k = i >> 8, n = i & 255;
        dst[(size_t)n * Kt + koff + k] = f2bf(src[i]);
    }
}

// ---------------- CSR mean gather: agg[row] = mean_{s in N(row)} h[s], bf16 ----------------
// one wave per row; lane covers 4 cols (8B); 4 edges in flight for L2/L3 latency
__global__ __launch_bounds__(256, 4) void k_gather(
    const unsigned short* __restrict__ h, const int* __restrict__ rp,
    const int* __restrict__ sl, unsigned short* __restrict__ agg, int nrows) {
    const int wv = threadIdx.x >> 6, l = threadIdx.x & 63;
    for (int row = blockIdx.x * 4 + wv; row < nrows; row += gridDim.x * 4) {
        int beg = rp[row], end = rp[row + 1];
        float a0 = 0, a1 = 0, a2 = 0, a3 = 0;
        int e = beg;
        #pragma unroll 1
        for (; e + 4 <= end; e += 4) {
            int s0 = sl[e], s1 = sl[e + 1], s2 = sl[e + 2], s3 = sl[e + 3];
            uint2 v0 = *(const uint2*)(h + (size_t)s0 * HD + 4 * l);
            uint2 v1 = *(const uint2*)(h + (size_t)s1 * HD + 4 * l);
            uint2 v2 = *(const uint2*)(h + (size_t)s2 * HD + 4 * l);
            uint2 v3 = *(const uint2*)(h + (size_t)s3 * HD + 4 * l);
            a0 += bflo(v0.x) + bflo(v1.x) + bflo(v2.x) + bflo(v3.x);
            a1 += bfhi(v0.x) + bfhi(v1.x) + bfhi(v2.x) + bfhi(v3.x);
            a2 += bflo(v0.y) + bflo(v1.y) + bflo(v2.y) + bflo(v3.y);
            a3 += bfhi(v0.y) + bfhi(v1.y) + bfhi(v2.y) + bfhi(v3.y);
        }
        #pragma unroll 1
        for (; e < end; ++e) {
            uint2 v = *(const uint2*)(h + (size_t)sl[e] * HD + 4 * l);
            a0 += bflo(v.x); a1 += bfhi(v.x); a2 += bflo(v.y); a3 += bfhi(v.y);
        }
        float inv = 1.0f / fmaxf((float)(end - beg), 1.0f);
        unsigned int lo = (unsigned int)f2bf(a0 * inv) | ((unsigned int)f2bf(a1 * inv) << 16);
        unsigned int hi = (unsigned int)f2bf(a2 * inv) | ((unsigned int)f2bf(a3 * inv) << 16);
        uint2 o = {lo, hi};
        *(uint2*)(agg + (size_t)row * HD + 4 * l) = o;
    }
}

// ---------------- MFMA GEMM, GELU epilogue, bf16 out ----------------
// C[M,256] = GELU([A1|A2] @ W + b). A split at k=K1 (A2 may be null / K2=0).
// WT is [256][Kt] bf16 (pre-transposed weights). BM=64, BN=256 (4 waves x 64 cols), BK=64.
// LDS xor-swizzle: 16B unit sg of row r lives at r*128 + ((sg^(r&7))*16) -> conflict-free
// b128 reads (each 16-lane group spans all 8 bank-quads) and writes.
__global__ __launch_bounds__(256, 3) void k_mm_gelu(
    const unsigned short* __restrict__ A1, const unsigned short* __restrict__ A2,
    int K1, int K2,
    const unsigned short* __restrict__ WT, const float* __restrict__ bias,
    unsigned short* __restrict__ out, int M) {
    const int Kt = K1 + K2;
    __shared__ char sm[BM * 128 + 256 * 128];  // A 8KB + B 32KB
    char* sA = sm;
    char* sB = sm + BM * 128;
    const int t = threadIdx.x;
    const int wv = t >> 6, l = t & 63;
    const int l15 = l & 15, lq = l >> 4;
    const int r0 = blockIdx.x * BM;

    f32x4 acc[4][4];
    #pragma unroll
    for (int i = 0; i < 4; ++i)
        #pragma unroll
        for (int j = 0; j < 4; ++j) acc[i][j] = (f32x4){0, 0, 0, 0};

    const int nchunks = Kt / BK;
    #pragma unroll 1
    for (int c = 0; c < nchunks; ++c) {
        const int k0 = c * BK;
        const unsigned short* Ap; int kloc, strideA;
        if (k0 < K1) { Ap = A1; kloc = k0;      strideA = K1; }
        else         { Ap = A2; kloc = k0 - K1; strideA = K2; }
        __syncthreads();  // WAR: prev iter's frag reads before restage
        #pragma unroll
        for (int j = 0; j < 2; ++j) {  // A: 512 16B units
            int u = t + 256 * j;
            int r = u >> 3, sg = u & 7;
            int gr = r0 + r; if (gr >= M) gr = M - 1;
            uint4 v = *(const uint4*)(Ap + (size_t)gr * strideA + kloc + sg * 8);
            *(uint4*)(sA + r * 128 + ((sg ^ (r & 7)) << 4)) = v;
        }
        #pragma unroll
        for (int j = 0; j < 8; ++j) {  // B: 2048 16B units
            int u = t + 256 * j;
            int n = u >> 3, sg = u & 7;
            uint4 v = *(const uint4*)(WT + (size_t)n * Kt + k0 + sg * 8);
            *(uint4*)(sB + n * 128 + ((sg ^ (n & 7)) << 4)) = v;
        }
        __syncthreads();
        #pragma unroll
        for (int ks = 0; ks < 2; ++ks) {
            bf16x8 af[4], bfr[4];
            int sg = ks * 4 + lq;
            #pragma unroll
            for (int mt = 0; mt < 4; ++mt) {
                int m = mt * 16 + l15;
                af[mt] = *(const bf16x8*)(sA + m * 128 + ((sg ^ (m & 7)) << 4));
            }
            #pragma unroll
            for (int nt = 0; nt < 4; ++nt) {
                int n = wv * 64 + nt * 16 + l15;
                bfr[nt] = *(const bf16x8*)(sB + n * 128 + ((sg ^ (n & 7)) << 4));
            }
            #pragma unroll
            for (int mt = 0; mt < 4; ++mt)
                #pragma unroll
                for (int nt = 0; nt < 4; ++nt)
                    acc[mt][nt] = __builtin_amdgcn_mfma_f32_16x16x32_bf16(
                        af[mt], bfr[nt], acc[mt][nt], 0, 0, 0);
        }
    }
    // epilogue: C/D layout col=lane&15, row=(lane>>4)*4+reg
    #pragma unroll
    for (int nt = 0; nt < 4; ++nt) {
        int col = wv * 64 + nt * 16 + l15;
        float bs = bias[col];
        #pragma unroll
        for (int mt = 0; mt < 4; ++mt) {
            int rowb = r0 + mt * 16 + lq * 4;
            #pragma unroll
            for (int rg = 0; rg < 4; ++rg) {
                int row = rowb + rg;
                if (row < M)
                    out[(size_t)row * HD + col] = f2bf(gelu_f(acc[mt][nt][rg] + bs));
            }
        }
    }
}

// ---------------- MFMA GEMM + LayerNorm epilogue, f32 out ----------------
// Each wave owns 16 rows x all 256 cols so LN row-reduction is wave-local
// (shuffle-xor over the 16-lane column group).
__global__ __launch_bounds__(256, 3) void k_mm_ln(
    const unsigned short* __restrict__ A, const unsigned short* __restrict__ WT,
    const float* __restrict__ bias, const float* __restrict__ g,
    const float* __restrict__ b2, float* __restrict__ out, int M) {
    const int Kt = HD;
    __shared__ char sm[BM * 128 + 256 * 128];
    char* sA = sm;
    char* sB = sm + BM * 128;
    const int t = threadIdx.x;
    const int wv = t >> 6, l = t & 63;
    const int l15 = l & 15, lq = l >> 4;
    const int r0 = blockIdx.x * BM;

    f32x4 acc[16];
    #pragma unroll
    for (int i = 0; i < 16; ++i) acc[i] = (f32x4){0, 0, 0, 0};

    #pragma unroll 1
    for (int c = 0; c < Kt / BK; ++c) {
        const int k0 = c * BK;
        __syncthreads();
        #pragma unroll
        for (int j = 0; j < 2; ++j) {
            int u = t + 256 * j;
            int r = u >> 3, sg = u & 7;
            int gr = r0 + r; if (gr >= M) gr = M - 1;
            uint4 v = *(const uint4*)(A + (size_t)gr * Kt + k0 + sg * 8);
            *(uint4*)(sA + r * 128 + ((sg ^ (r & 7)) << 4)) = v;
        }
        #pragma unroll
        for (int j = 0; j < 8; ++j) {
            int u = t + 256 * j;
            int n = u >> 3, sg = u & 7;
            uint4 v = *(const uint4*)(WT + (size_t)n * Kt + k0 + sg * 8);
            *(uint4*)(sB + n * 128 + ((sg ^ (n & 7)) << 4)) = v;
        }
        __syncthreads();
        #pragma unroll
        for (int ks = 0; ks < 2; ++ks) {
            int sg = ks * 4 + lq;
            int m = wv * 16 + l15;  // this wave's 16 rows
            bf16x8 af = *(const bf16x8*)(sA + m * 128 + ((sg ^ (m & 7)) << 4));
            #pragma unroll
            for (int nt = 0; nt < 16; ++nt) {
                int n = nt * 16 + l15;
                bf16x8 bfr = *(const bf16x8*)(sB + n * 128 + ((sg ^ (n & 7)) << 4));
                acc[nt] = __builtin_amdgcn_mfma_f32_16x16x32_bf16(af, bfr, acc[nt], 0, 0, 0);
            }
        }
    }
    // bias + LN. Lane holds rows (wv*16 + lq*4 + rg), cols (nt*16 + l15).
    #pragma unroll
    for (int nt = 0; nt < 16; ++nt) {
        float bs = bias[nt * 16 + l15];
        #pragma unroll
        for (int rg = 0; rg < 4; ++rg) acc[nt][rg] += bs;
    }
    float s0 = 0, s1 = 0, s2 = 0, s3 = 0;
    #pragma unroll
    for (int nt = 0; nt < 16; ++nt) { s0 += acc[nt][0]; s1 += acc[nt][1]; s2 += acc[nt][2]; s3 += acc[nt][3]; }
    #pragma unroll
    for (int off = 1; off < 16; off <<= 1) {
        s0 += __shfl_xor(s0, off, 64); s1 += __shfl_xor(s1, off, 64);
        s2 += __shfl_xor(s2, off, 64); s3 += __shfl_xor(s3, off, 64);
    }
    const float mu0 = s0 * (1.0f / HD), mu1 = s1 * (1.0f / HD),
                mu2 = s2 * (1.0f / HD), mu3 = s3 * (1.0f / HD);
    float q0 = 0, q1 = 0, q2 = 0, q3 = 0;
    #pragma unroll
    for (int nt = 0; nt < 16; ++nt) {
        float d0 = acc[nt][0] - mu0, d1 = acc[nt][1] - mu1,
              d2 = acc[nt][2] - mu2, d3 = acc[nt][3] - mu3;
        q0 += d0 * d0; q1 += d1 * d1; q2 += d2 * d2; q3 += d3 * d3;
    }
    #pragma unroll
    for (int off = 1; off < 16; off <<= 1) {
        q0 += __shfl_xor(q0, off, 64); q1 += __shfl_xor(q1, off, 64);
        q2 += __shfl_xor(q2, off, 64); q3 += __shfl_xor(q3, off, 64);
    }
    const float rs0 = rsqrtf(q0 * (1.0f / HD) + 1e-5f), rs1 = rsqrtf(q1 * (1.0f / HD) + 1e-5f),
                rs2 = rsqrtf(q2 * (1.0f / HD) + 1e-5f), rs3 = rsqrtf(q3 * (1.0f / HD) + 1e-5f);
    const int rowb = r0 + wv * 16 + lq * 4;
    #pragma unroll
    for (int nt = 0; nt < 16; ++nt) {
        int col = nt * 16 + l15;
        float gg = g[col], bb = b2[col];
        float mu[4] = {mu0, mu1, mu2, mu3};
        float rs[4] = {rs0, rs1, rs2, rs3};
        #pragma unroll
        for (int rg = 0; rg < 4; ++rg) {
            int row = rowb + rg;
            if (row < M)
                out[(size_t)row * HD + col] = (acc[nt][rg] - mu[rg]) * rs[rg] * gg + bb;
        }
    }
}

extern "C" void kernel_launch(void* const* d_in, const int* in_sizes, int n_in,
                              void* d_out, int out_size, void* d_ws, size_t ws_size,
                              hipStream_t stream) {
    const float* x_user     = (const float*)d_in[0];
    const float* x_item     = (const float*)d_in[1];
    const int*   ei_ui_src  = (const int*)d_in[2];
    const int*   ei_ui_dst  = (const int*)d_in[3];
    const int*   ei_iu_src  = (const int*)d_in[4];
    const int*   ei_iu_dst  = (const int*)d_in[5];
    const float* lin_user_W = (const float*)d_in[6];
    const float* lin_user_b = (const float*)d_in[7];
    const float* lin_item_W = (const float*)d_in[8];
    const float* lin_item_b = (const float*)d_in[9];
    const float* c0_ui_Wl = (const float*)d_in[10];
    const float* c0_ui_bl = (const float*)d_in[11];
    const float* c0_ui_Wr = (const float*)d_in[12];
    const float* c0_iu_Wl = (const float*)d_in[13];
    const float* c0_iu_bl = (const float*)d_in[14];
    const float* c0_iu_Wr = (const float*)d_in[15];
    const float* c1_ui_Wl = (const float*)d_in[16];
    const float* c1_ui_bl = (const float*)d_in[17];
    const float* c1_ui_Wr = (const float*)d_in[18];
    const float* c1_iu_Wl = (const float*)d_in[19];
    const float* c1_iu_bl = (const float*)d_in[20];
    const float* c1_iu_Wr = (const float*)d_in[21];
    const float* out_user_W = (const float*)d_in[22];
    const float* out_user_b = (const float*)d_in[23];
    const float* out_item_W = (const float*)d_in[24];
    const float* out_item_b = (const float*)d_in[25];
    const float* ln_user_g  = (const float*)d_in[26];
    const float* ln_user_b2 = (const float*)d_in[27];
    const float* ln_item_g  = (const float*)d_in[28];
    const float* ln_item_b2 = (const float*)d_in[29];

    char* ws = (char*)d_ws;
    size_t off = 0;
    auto alloc = [&](size_t bytes) -> void* {
        void* p = ws + off;
        off += (bytes + 255) & ~(size_t)255;
        return p;
    };
    typedef unsigned short u16;
    u16* xb_u = (u16*)alloc((size_t)NUSER * DIN * 2);
    u16* xb_i = (u16*)alloc((size_t)NITEM * DIN * 2);
    u16* hu_a = (u16*)alloc((size_t)NUSER * HD * 2);
    u16* hi_a = (u16*)alloc((size_t)NITEM * HD * 2);
    u16* agg  = (u16*)alloc((size_t)NUSER * HD * 2);   // shared: convs run sequentially
    u16* WT_lu   = (u16*)alloc((size_t)HD * DIN * 2);
    u16* WT_li   = (u16*)alloc((size_t)HD * DIN * 2);
    u16* WT_c0ui = (u16*)alloc((size_t)HD * 2 * HD * 2);
    u16* WT_c0iu = (u16*)alloc((size_t)HD * 2 * HD * 2);
    u16* WT_c1ui = (u16*)alloc((size_t)HD * 2 * HD * 2);
    u16* WT_c1iu = (u16*)alloc((size_t)HD * 2 * HD * 2);
    u16* WT_ou   = (u16*)alloc((size_t)HD * HD * 2);
    u16* WT_oi   = (u16*)alloc((size_t)HD * HD * 2);
    int* rp_i  = (int*)alloc((NITEM + 1) * 4);
    int* rp_u  = (int*)alloc((NUSER + 1) * 4);
    int* cur_i = (int*)alloc(NITEM * 4);
    int* cur_u = (int*)alloc(NUSER * 4);
    int* cnt_i = (int*)alloc(NITEM * 4);
    int* cnt_u = (int*)alloc(NUSER * 4);
    int* sl_ui = (int*)alloc((size_t)NEDGE * 4);
    int* sl_iu = (int*)alloc((size_t)NEDGE * 4);
    int* csum_i = (int*)alloc(64 * 4);
    int* csum_u = (int*)alloc(64 * 4);

    // h pong buffers (bf16) live in d_out's 204.8MB; heads overwrite d_out last
    u16* hu_b = (u16*)d_out;
    u16* hi_b = (u16*)d_out + (size_t)NUSER * HD;

    const int MMG = (NUSER + BM - 1) / BM;  // == for NITEM too
    const int NBI = (NITEM + SCHUNK - 1) / SCHUNK;
    const int NBU = (NUSER + SCHUNK - 1) / SCHUNK;

    // ---- CSR build ----
    hipMemsetAsync(cnt_i, 0, NITEM * 4, stream);
    hipMemsetAsync(cnt_u, 0, NUSER * 4, stream);
    k_hist<<<1024, 256, 0, stream>>>(ei_ui_dst, cnt_i, NEDGE);
    k_hist<<<1024, 256, 0, stream>>>(ei_iu_dst, cnt_u, NEDGE);
    k_scan_part<<<NBI + NBU, 1024, 0, stream>>>(cnt_i, rp_i, NITEM, NBI, csum_i,
                                                cnt_u, rp_u, NUSER, csum_u);
    k_scan_fin<<<NBI + NBU, 1024, 0, stream>>>(rp_i, cur_i, NITEM, NBI, csum_i,
                                               rp_u, cur_u, NUSER, NBU, csum_u);
    k_scatter<<<1024, 256, 0, stream>>>(ei_ui_src, ei_ui_dst, cur_i, sl_ui, NEDGE);
    k_scatter<<<1024, 256, 0, stream>>>(ei_iu_src, ei_iu_dst, cur_u, sl_iu, NEDGE);

    // ---- dtype prep (bf16 x, transposed bf16 weights) ----
    k_cvt<<<(NUSER * DIN / 4 + 255) / 256, 256, 0, stream>>>(x_user, xb_u, NUSER * DIN / 4);
    k_cvt<<<(NITEM * DIN / 4 + 255) / 256, 256, 0, stream>>>(x_item, xb_i, NITEM * DIN / 4);
    k_cvtT<<<DIN, 256, 0, stream>>>(lin_user_W, WT_lu, DIN, DIN, 0);
    k_cvtT<<<DIN, 256, 0, stream>>>(lin_item_W, WT_li, DIN, DIN, 0);
    k_cvtT<<<HD, 256, 0, stream>>>(c0_ui_Wl, WT_c0ui, HD, 2 * HD, 0);
    k_cvtT<<<HD, 256, 0, stream>>>(c0_ui_Wr, WT_c0ui, HD, 2 * HD, HD);
    k_cvtT<<<HD, 256, 0, stream>>>(c0_iu_Wl, WT_c0iu, HD, 2 * HD, 0);
    k_cvtT<<<HD, 256, 0, stream>>>(c0_iu_Wr, WT_c0iu, HD, 2 * HD, HD);
    k_cvtT<<<HD, 256, 0, stream>>>(c1_ui_Wl, WT_c1ui, HD, 2 * HD, 0);
    k_cvtT<<<HD, 256, 0, stream>>>(c1_ui_Wr, WT_c1ui, HD, 2 * HD, HD);
    k_cvtT<<<HD, 256, 0, stream>>>(c1_iu_Wl, WT_c1iu, HD, 2 * HD, 0);
    k_cvtT<<<HD, 256, 0, stream>>>(c1_iu_Wr, WT_c1iu, HD, 2 * HD, HD);
    k_cvtT<<<HD, 256, 0, stream>>>(out_user_W, WT_ou, HD, HD, 0);
    k_cvtT<<<HD, 256, 0, stream>>>(out_item_W, WT_oi, HD, HD, 0);

    // ---- input projections ----
    k_mm_gelu<<<MMG, 256, 0, stream>>>(xb_u, (const u16*)nullptr, DIN, 0, WT_lu, lin_user_b, hu_a, NUSER);
    k_mm_gelu<<<MMG, 256, 0, stream>>>(xb_i, (const u16*)nullptr, DIN, 0, WT_li, lin_item_b, hi_a, NITEM);

    // ---- layer 0 ----
    k_gather<<<4096, 256, 0, stream>>>(hu_a, rp_i, sl_ui, agg, NITEM);
    k_mm_gelu<<<MMG, 256, 0, stream>>>(agg, hi_a, HD, HD, WT_c0ui, c0_ui_bl, hi_b, NITEM);
    k_gather<<<4096, 256, 0, stream>>>(hi_a, rp_u, sl_iu, agg, NUSER);
    k_mm_gelu<<<MMG, 256, 0, stream>>>(agg, hu_a, HD, HD, WT_c0iu, c0_iu_bl, hu_b, NUSER);

    // ---- layer 1 ----
    k_gather<<<4096, 256, 0, stream>>>(hu_b, rp_i, sl_ui, agg, NITEM);
    k_mm_gelu<<<MMG, 256, 0, stream>>>(agg, hi_b, HD, HD, WT_c1ui, c1_ui_bl, hi_a, NITEM);
    k_gather<<<4096, 256, 0, stream>>>(hi_b, rp_u, sl_iu, agg, NUSER);
    k_mm_gelu<<<MMG, 256, 0, stream>>>(agg, hu_b, HD, HD, WT_c1iu, c1_iu_bl, hu_a, NUSER);

    // ---- heads + LayerNorm (read ws, write d_out) ----
    k_mm_ln<<<MMG, 256, 0, stream>>>(hu_a, WT_ou, out_user_b, ln_user_g, ln_user_b2,
                                     (float*)d_out, NUSER);
    k_mm_ln<<<MMG, 256, 0, stream>>>(hi_a, WT_oi, out_item_b, ln_item_g, ln_item_b2,
                                     (float*)d_out + (size_t)NUSER * HD, NITEM);
}